// Round 6
// baseline (681.340 us; speedup 1.0000x reference)
//
#include <hip/hip_runtime.h>
#include <hip/hip_bf16.h>

#define NROWS 8192
#define DDIM 768

typedef short short8 __attribute__((ext_vector_type(8)));   // 8 x bf16 (4 VGPRs)
typedef float floatx4 __attribute__((ext_vector_type(4)));  // MFMA C/D
typedef unsigned long long u64;
typedef unsigned int u32;
typedef u32 u32x4 __attribute__((ext_vector_type(4)));      // 16B packed-mask chunk

// ---------------------------------------------------------------------------
// Kernel 1: row-normalize features (fp32 in) -> bf16 normalized rows
// ---------------------------------------------------------------------------
__global__ __launch_bounds__(256) void normalize_k(const float* __restrict__ f,
                                                   __hip_bfloat16* __restrict__ fn) {
    const int row = blockIdx.x;
    const int t = threadIdx.x;
    const float* fr = f + (size_t)row * DDIM;
    float v0 = fr[t];
    float v1 = fr[t + 256];
    float v2 = fr[t + 512];
    float ss = v0 * v0 + v1 * v1 + v2 * v2;
#pragma unroll
    for (int m = 32; m; m >>= 1) ss += __shfl_xor(ss, m, 64);
    __shared__ float wsum[4];
    if ((t & 63) == 0) wsum[t >> 6] = ss;
    __syncthreads();
    float tot = wsum[0] + wsum[1] + wsum[2] + wsum[3];
    float inv = 1.0f / fmaxf(sqrtf(tot), 1e-8f);
    __hip_bfloat16* o = fn + (size_t)row * DDIM;
    o[t]       = __float2bfloat16(v0 * inv);
    o[t + 256] = __float2bfloat16(v1 * inv);
    o[t + 512] = __float2bfloat16(v2 * inv);
}

// ---------------------------------------------------------------------------
// Kernel 2: pack masks to bits + per-row positive count (diag excluded).
// R6: g-loop unrolled x8 with all 16 float4 loads issued before any ballot
// (R5 was 2-loads-in-flight latency-bound at 3.25 TB/s true read rate).
// u32 layout: word[((row*32+g)*2+hi)*4 + reg] bit l = element 256g+128hi+4l+reg.
// ---------------------------------------------------------------------------
__global__ __launch_bounds__(256) void pack_k(const float* __restrict__ pm,
                                              const float* __restrict__ nm,
                                              u32* __restrict__ pmw,
                                              u32* __restrict__ nmw,
                                              float* __restrict__ pG) {
    const int lane = threadIdx.x & 63;
    const int wv = threadIdx.x >> 6;
    const int row = blockIdx.x * 4 + wv;
    const float4* pr = (const float4*)(pm + (size_t)row * NROWS);
    const float4* nr = (const float4*)(nm + (size_t)row * NROWS);
    const int dg = row >> 8;                       // superblock holding diag
    const u64 dclear = ~(1ull << ((row & 255) >> 2));
    int pc = 0;
    for (int g0 = 0; g0 < 32; g0 += 8) {
        float4 pv[8], nv[8];
#pragma unroll
        for (int u = 0; u < 8; ++u) {
            pv[u] = pr[(size_t)(g0 + u) * 64 + lane];
            nv[u] = nr[(size_t)(g0 + u) * 64 + lane];
        }
#pragma unroll
        for (int u = 0; u < 8; ++u) {
            const int g = g0 + u;
            u64 pb0 = __ballot(pv[u].x != 0.f), pb1 = __ballot(pv[u].y != 0.f);
            u64 pb2 = __ballot(pv[u].z != 0.f), pb3 = __ballot(pv[u].w != 0.f);
            u64 nb0 = __ballot(nv[u].x != 0.f), nb1 = __ballot(nv[u].y != 0.f);
            u64 nb2 = __ballot(nv[u].z != 0.f), nb3 = __ballot(nv[u].w != 0.f);
            if (g == dg) {                         // zero the diagonal bit
                const int dk = row & 3;
                if (dk == 0) { pb0 &= dclear; nb0 &= dclear; }
                else if (dk == 1) { pb1 &= dclear; nb1 &= dclear; }
                else if (dk == 2) { pb2 &= dclear; nb2 &= dclear; }
                else { pb3 &= dclear; nb3 &= dclear; }
            }
            pc += __popcll(pb0) + __popcll(pb1) + __popcll(pb2) + __popcll(pb3);
            const size_t wi = ((size_t)row * 32 + g) * 8;   // u32 index
            if (lane == 0) {
                *(u32x4*)(pmw + wi)     = (u32x4){(u32)pb0, (u32)pb1, (u32)pb2, (u32)pb3};
                *(u32x4*)(pmw + wi + 4) = (u32x4){(u32)(pb0 >> 32), (u32)(pb1 >> 32),
                                                  (u32)(pb2 >> 32), (u32)(pb3 >> 32)};
            } else if (lane == 1) {
                *(u32x4*)(nmw + wi)     = (u32x4){(u32)nb0, (u32)nb1, (u32)nb2, (u32)nb3};
                *(u32x4*)(nmw + wi + 4) = (u32x4){(u32)(nb0 >> 32), (u32)(nb1 >> 32),
                                                  (u32)(nb2 >> 32), (u32)(nb3 >> 32)};
            }
        }
    }
    if (lane == 0) pG[row] = (float)pc;
}

// ---------------------------------------------------------------------------
// Kernel 3: bf16 GEMM (s = 10 * fn fn^T) + bit-masked row reductions.
// One 128x128 tile per block, BK=32, conflict-free XOR swizzle,
// __launch_bounds__(256,4). UNCHANGED from R5 (the win config).
// ---------------------------------------------------------------------------
__global__ __launch_bounds__(256, 4) void ntxent_main(
        const __hip_bfloat16* __restrict__ fn,
        const u32* __restrict__ pmw, const u32* __restrict__ nmw,
        float* __restrict__ negG, float* __restrict__ sG) {
    __shared__ __hip_bfloat16 Is[128 * 32];   // 8 KB
    __shared__ __hip_bfloat16 Js[128 * 32];   // 8 KB

    const int t = threadIdx.x;
    const int lane = t & 63;
    const int wv = t >> 6;
    const int wm = wv & 1;           // wave's j-half
    const int wn = wv >> 1;          // wave's i-half
    const int q  = lane >> 4;
    const int cl = lane & 15;
    const int rowBase = blockIdx.y * 128;
    const int colBase = blockIdx.x * 128;

    const int rdSw = ((q ^ ((cl >> 1) & 3)) << 4);

    floatx4 acc[4][4];            // [mf (j)][nf (i)]
#pragma unroll
    for (int mf = 0; mf < 4; ++mf)
#pragma unroll
        for (int nf = 0; nf < 4; ++nf)
            acc[mf][nf] = (floatx4){0.f, 0.f, 0.f, 0.f};

    for (int k0 = 0; k0 < DDIM; k0 += 32) {
        __syncthreads();
#pragma unroll
        for (int it = 0; it < 2; ++it) {
            const int s = it * 256 + t;              // 16B slot 0..511
            const int r = s >> 2;
            const int cg = (s & 3) ^ ((r >> 1) & 3); // swizzled src chunk
            const __hip_bfloat16* ga = fn + (size_t)(rowBase + r) * DDIM + k0 + cg * 8;
            const __hip_bfloat16* gb = fn + (size_t)(colBase + r) * DDIM + k0 + cg * 8;
            __builtin_amdgcn_global_load_lds(
                (const __attribute__((address_space(1))) void*)ga,
                (__attribute__((address_space(3))) void*)((char*)Is + s * 16), 16, 0, 0);
            __builtin_amdgcn_global_load_lds(
                (const __attribute__((address_space(1))) void*)gb,
                (__attribute__((address_space(3))) void*)((char*)Js + s * 16), 16, 0, 0);
        }
        __syncthreads();

        short8 jf[4], if_[4];
#pragma unroll
        for (int mf = 0; mf < 4; ++mf) {
            const int r = wm * 64 + mf * 16 + cl;
            jf[mf] = *(const short8*)((const char*)Js + r * 64 + rdSw);
        }
#pragma unroll
        for (int nf = 0; nf < 4; ++nf) {
            const int r = wn * 64 + nf * 16 + cl;
            if_[nf] = *(const short8*)((const char*)Is + r * 64 + rdSw);
        }
#pragma unroll
        for (int mf = 0; mf < 4; ++mf)
#pragma unroll
            for (int nf = 0; nf < 4; ++nf)
                acc[mf][nf] = __builtin_amdgcn_mfma_f32_16x16x32_bf16(
                    jf[mf], if_[nf], acc[mf][nf], 0, 0, 0);
    }

    // ---- epilogue (once per block) ----
    const int col64 = colBase + wm * 64;
    const int g = col64 >> 8;            // 256-col superblock
    const int a = (col64 >> 6) & 3;      // 64-col slot
    const int hi = a >> 1;               // u32 half of each u64 word
    const int shb = (a & 1) * 16 + q;    // + mf*4 below
#pragma unroll
    for (int nf = 0; nf < 4; ++nf) {
        const int grow = rowBase + wn * 64 + nf * 16 + cl;
        const size_t mb = ((size_t)grow * 32 + g) * 8 + hi * 4;
        u32x4 pu = *(const u32x4*)(pmw + mb);
        u32x4 nu = *(const u32x4*)(nmw + mb);
        float aN = 0.f, aS = 0.f;
#pragma unroll
        for (int mf = 0; mf < 4; ++mf) {
            const int sh = shb + mf * 4;
#pragma unroll
            for (int reg = 0; reg < 4; ++reg) {
                float v = acc[mf][nf][reg];
                float e = __builtin_amdgcn_exp2f(v * 14.4269504089f); // e^(10v)
                float pb = (float)((pu[reg] >> sh) & 1u);
                float nb = (float)((nu[reg] >> sh) & 1u);
                aN = fmaf(nb, e, aN);
                aS = fmaf(pb, v, aS);     // raw acc units; x10 in final_k
            }
        }
        aN += __shfl_xor(aN, 16, 64);  aN += __shfl_xor(aN, 32, 64);
        aS += __shfl_xor(aS, 16, 64);  aS += __shfl_xor(aS, 32, 64);
        if (q == 0) {
            atomicAdd(&negG[grow], aN);
            atomicAdd(&sG[grow],   aS);
        }
    }
}

// ---------------------------------------------------------------------------
// Kernel 4: per-row loss assembly + mean
// ---------------------------------------------------------------------------
__global__ __launch_bounds__(1024) void final_k(const float* __restrict__ negG,
        const float* __restrict__ sG, const float* __restrict__ pG,
        float* __restrict__ out) {
    const int t = threadIdx.x;
    float sum = 0.f;
    for (int i = t; i < NROWS; i += 1024) {
        float P = pG[i];
        if (P > 0.f) {
            sum += (P * logf(negG[i]) - 10.0f * sG[i]) / P;
        }
    }
#pragma unroll
    for (int m = 32; m; m >>= 1) sum += __shfl_xor(sum, m, 64);
    __shared__ float wsum[16];
    if ((t & 63) == 0) wsum[t >> 6] = sum;
    __syncthreads();
    if (t < 16) {
        float v = wsum[t];
#pragma unroll
        for (int m = 8; m; m >>= 1) v += __shfl_xor(v, m, 16);
        if (t == 0) out[0] = v / (float)NROWS;
    }
}

// ---------------------------------------------------------------------------
extern "C" void kernel_launch(void* const* d_in, const int* in_sizes, int n_in,
                              void* d_out, int out_size, void* d_ws, size_t ws_size,
                              hipStream_t stream) {
    const float* feat  = (const float*)d_in[0];
    const float* pmask = (const float*)d_in[1];
    const float* nmask = (const float*)d_in[2];
    float* out = (float*)d_out;

    char* ws = (char*)d_ws;
    __hip_bfloat16* fn = (__hip_bfloat16*)ws;                    // 12,582,912 B
    u32* pmw = (u32*)(ws + 12582912);                            //  8,388,608 B
    u32* nmw = (u32*)(ws + 12582912 + 8388608);                  //  8,388,608 B
    float* negG = (float*)(ws + 12582912 + 2 * 8388608);
    float* sG = negG + NROWS;
    float* pG = sG + NROWS;

    // zero the two GEMM-side accumulators (pG fully written by pack_k)
    hipMemsetAsync(negG, 0, 2 * NROWS * sizeof(float), stream);

    normalize_k<<<NROWS, 256, 0, stream>>>(feat, fn);
    pack_k<<<NROWS / 4, 256, 0, stream>>>(pmask, nmask, pmw, nmw, pG);

    dim3 grid(64, 64);   // one 128x128 tile per block
    ntxent_main<<<grid, 256, 0, stream>>>(fn, pmw, nmw, negG, sG);

    final_k<<<1, 1024, 0, stream>>>(negG, sG, pG, out);
}

// Round 7
// 605.927 us; speedup vs baseline: 1.1245x; 1.1245x over previous
//
#include <hip/hip_runtime.h>
#include <hip/hip_bf16.h>

#define NROWS 8192
#define DDIM 768

typedef short short8 __attribute__((ext_vector_type(8)));   // 8 x bf16 (4 VGPRs)
typedef float floatx4 __attribute__((ext_vector_type(4)));  // MFMA C/D

// ---------------------------------------------------------------------------
// Kernel 1: row-normalize features (fp32 in) -> bf16 normalized rows
// ---------------------------------------------------------------------------
__global__ __launch_bounds__(256) void normalize_k(const float* __restrict__ f,
                                                   __hip_bfloat16* __restrict__ fn) {
    const int row = blockIdx.x;
    const int t = threadIdx.x;
    const float* fr = f + (size_t)row * DDIM;
    float v0 = fr[t];
    float v1 = fr[t + 256];
    float v2 = fr[t + 512];
    float ss = v0 * v0 + v1 * v1 + v2 * v2;
#pragma unroll
    for (int m = 32; m; m >>= 1) ss += __shfl_xor(ss, m, 64);
    __shared__ float wsum[4];
    if ((t & 63) == 0) wsum[t >> 6] = ss;
    __syncthreads();
    float tot = wsum[0] + wsum[1] + wsum[2] + wsum[3];
    float inv = 1.0f / fmaxf(sqrtf(tot), 1e-8f);
    __hip_bfloat16* o = fn + (size_t)row * DDIM;
    o[t]       = __float2bfloat16(v0 * inv);
    o[t + 256] = __float2bfloat16(v1 * inv);
    o[t + 512] = __float2bfloat16(v2 * inv);
}

// ---------------------------------------------------------------------------
// Kernel 2: bf16 GEMM (s = 10 * fn fn^T) + FUSED raw-fp32-mask row reductions.
// R7: pack_k deleted — each mask element is consumed exactly once, so the
// epilogue reads pmask/nmask directly (float4, full 64B-line utilization).
// The 536 MB mask stream overlaps MFMA compute across the ~16 pipelined
// block-generations per CU instead of serializing as a separate pass.
// One 128x128 tile per block, BK=32, conflict-free XOR swizzle,
// __launch_bounds__(256,4) — the R5 win config, K-loop untouched.
// D[m=j][n=i]: j = colBase+wm*64+mf*16+q*4+reg, i = rowBase+wn*64+nf*16+cl.
// ---------------------------------------------------------------------------
__global__ __launch_bounds__(256, 4) void ntxent_main(
        const __hip_bfloat16* __restrict__ fn,
        const float* __restrict__ pmask, const float* __restrict__ nmask,
        float* __restrict__ negG, float* __restrict__ sG,
        float* __restrict__ pG) {
    __shared__ __hip_bfloat16 Is[128 * 32];   // 8 KB
    __shared__ __hip_bfloat16 Js[128 * 32];   // 8 KB

    const int t = threadIdx.x;
    const int lane = t & 63;
    const int wv = t >> 6;
    const int wm = wv & 1;           // wave's j-half
    const int wn = wv >> 1;          // wave's i-half
    const int q  = lane >> 4;
    const int cl = lane & 15;
    const int rowBase = blockIdx.y * 128;
    const int colBase = blockIdx.x * 128;

    const int rdSw = ((q ^ ((cl >> 1) & 3)) << 4);

    floatx4 acc[4][4];            // [mf (j)][nf (i)]
#pragma unroll
    for (int mf = 0; mf < 4; ++mf)
#pragma unroll
        for (int nf = 0; nf < 4; ++nf)
            acc[mf][nf] = (floatx4){0.f, 0.f, 0.f, 0.f};

    for (int k0 = 0; k0 < DDIM; k0 += 32) {
        __syncthreads();
#pragma unroll
        for (int it = 0; it < 2; ++it) {
            const int s = it * 256 + t;              // 16B slot 0..511
            const int r = s >> 2;
            const int cg = (s & 3) ^ ((r >> 1) & 3); // swizzled src chunk
            const __hip_bfloat16* ga = fn + (size_t)(rowBase + r) * DDIM + k0 + cg * 8;
            const __hip_bfloat16* gb = fn + (size_t)(colBase + r) * DDIM + k0 + cg * 8;
            __builtin_amdgcn_global_load_lds(
                (const __attribute__((address_space(1))) void*)ga,
                (__attribute__((address_space(3))) void*)((char*)Is + s * 16), 16, 0, 0);
            __builtin_amdgcn_global_load_lds(
                (const __attribute__((address_space(1))) void*)gb,
                (__attribute__((address_space(3))) void*)((char*)Js + s * 16), 16, 0, 0);
        }
        __syncthreads();

        short8 jf[4], if_[4];
#pragma unroll
        for (int mf = 0; mf < 4; ++mf) {
            const int r = wm * 64 + mf * 16 + cl;
            jf[mf] = *(const short8*)((const char*)Js + r * 64 + rdSw);
        }
#pragma unroll
        for (int nf = 0; nf < 4; ++nf) {
            const int r = wn * 64 + nf * 16 + cl;
            if_[nf] = *(const short8*)((const char*)Is + r * 64 + rdSw);
        }
#pragma unroll
        for (int mf = 0; mf < 4; ++mf)
#pragma unroll
            for (int nf = 0; nf < 4; ++nf)
                acc[mf][nf] = __builtin_amdgcn_mfma_f32_16x16x32_bf16(
                    jf[mf], if_[nf], acc[mf][nf], 0, 0, 0);
    }

    // ---- epilogue (once per block): raw fp32 mask loads ----
    const int col64 = colBase + wm * 64;
    const int jb0 = col64 + q * 4;           // + mf*16 below; 4 consecutive j
#pragma unroll
    for (int nf = 0; nf < 4; ++nf) {
        const int grow = rowBase + wn * 64 + nf * 16 + cl;
        const float* prow = pmask + (size_t)grow * NROWS;
        const float* nrow = nmask + (size_t)grow * NROWS;
        float4 pm4[4], nm4[4];
#pragma unroll
        for (int mf = 0; mf < 4; ++mf) {      // issue all 8 loads up front
            pm4[mf] = *(const float4*)(prow + jb0 + mf * 16);
            nm4[mf] = *(const float4*)(nrow + jb0 + mf * 16);
        }
        float aN = 0.f, aS = 0.f, aP = 0.f;
#pragma unroll
        for (int mf = 0; mf < 4; ++mf) {
            const int jbase = jb0 + mf * 16;
#pragma unroll
            for (int reg = 0; reg < 4; ++reg) {
                float pmv = ((const float*)&pm4[mf])[reg];
                float nmv = ((const float*)&nm4[mf])[reg];
                if (grow == jbase + reg) { pmv = 0.f; nmv = 0.f; }  // diagonal
                float v = acc[mf][nf][reg];
                float e = __builtin_amdgcn_exp2f(v * 14.4269504089f); // e^(10v)
                aN = fmaf(nmv, e, aN);
                aS = fmaf(pmv, v, aS);       // raw acc units; x10 in final_k
                aP += pmv;
            }
        }
        aN += __shfl_xor(aN, 16, 64);  aN += __shfl_xor(aN, 32, 64);
        aS += __shfl_xor(aS, 16, 64);  aS += __shfl_xor(aS, 32, 64);
        aP += __shfl_xor(aP, 16, 64);  aP += __shfl_xor(aP, 32, 64);
        if (q == 0) {
            atomicAdd(&negG[grow], aN);
            atomicAdd(&sG[grow],   aS);
            atomicAdd(&pG[grow],   aP);
        }
    }
}

// ---------------------------------------------------------------------------
// Kernel 3: per-row loss assembly + mean
// loss_i = (P*log(neg) - 10*S_raw)/P (P>0 else 0);  out = mean
// ---------------------------------------------------------------------------
__global__ __launch_bounds__(1024) void final_k(const float* __restrict__ negG,
        const float* __restrict__ sG, const float* __restrict__ pG,
        float* __restrict__ out) {
    const int t = threadIdx.x;
    float sum = 0.f;
    for (int i = t; i < NROWS; i += 1024) {
        float P = pG[i];
        if (P > 0.f) {
            sum += (P * logf(negG[i]) - 10.0f * sG[i]) / P;
        }
    }
#pragma unroll
    for (int m = 32; m; m >>= 1) sum += __shfl_xor(sum, m, 64);
    __shared__ float wsum[16];
    if ((t & 63) == 0) wsum[t >> 6] = sum;
    __syncthreads();
    if (t < 16) {
        float v = wsum[t];
#pragma unroll
        for (int m = 8; m; m >>= 1) v += __shfl_xor(v, m, 16);
        if (t == 0) out[0] = v / (float)NROWS;
    }
}

// ---------------------------------------------------------------------------
extern "C" void kernel_launch(void* const* d_in, const int* in_sizes, int n_in,
                              void* d_out, int out_size, void* d_ws, size_t ws_size,
                              hipStream_t stream) {
    const float* feat  = (const float*)d_in[0];
    const float* pmask = (const float*)d_in[1];
    const float* nmask = (const float*)d_in[2];
    float* out = (float*)d_out;

    char* ws = (char*)d_ws;
    __hip_bfloat16* fn = (__hip_bfloat16*)ws;                    // 12,582,912 B
    float* negG = (float*)(ws + 12582912);
    float* sG = negG + NROWS;
    float* pG = sG + NROWS;

    // zero all three row accumulators (ws is re-poisoned before every launch)
    hipMemsetAsync(negG, 0, 3 * NROWS * sizeof(float), stream);

    normalize_k<<<NROWS, 256, 0, stream>>>(feat, fn);

    dim3 grid(64, 64);   // one 128x128 tile per block
    ntxent_main<<<grid, 256, 0, stream>>>(fn, pmask, nmask, negG, sG, pG);

    final_k<<<1, 1024, 0, stream>>>(negG, sG, pG, out);
}

// Round 8
// 586.094 us; speedup vs baseline: 1.1625x; 1.0338x over previous
//
#include <hip/hip_runtime.h>
#include <hip/hip_bf16.h>

#define NROWS 8192
#define DDIM 768

typedef short short8 __attribute__((ext_vector_type(8)));   // 8 x bf16 (4 VGPRs)
typedef float floatx4 __attribute__((ext_vector_type(4)));  // MFMA C/D
#define TSTRIDE 132   // transpose LDS row stride (floats): 2-way banks, 16B aligned

// ---------------------------------------------------------------------------
// Kernel 1: row-normalize features (fp32 in) -> bf16 normalized rows
// ---------------------------------------------------------------------------
__global__ __launch_bounds__(256) void normalize_k(const float* __restrict__ f,
                                                   __hip_bfloat16* __restrict__ fn) {
    const int row = blockIdx.x;
    const int t = threadIdx.x;
    const float* fr = f + (size_t)row * DDIM;
    float v0 = fr[t];
    float v1 = fr[t + 256];
    float v2 = fr[t + 512];
    float ss = v0 * v0 + v1 * v1 + v2 * v2;
#pragma unroll
    for (int m = 32; m; m >>= 1) ss += __shfl_xor(ss, m, 64);
    __shared__ float wsum[4];
    if ((t & 63) == 0) wsum[t >> 6] = ss;
    __syncthreads();
    float tot = wsum[0] + wsum[1] + wsum[2] + wsum[3];
    float inv = 1.0f / fmaxf(sqrtf(tot), 1e-8f);
    __hip_bfloat16* o = fn + (size_t)row * DDIM;
    o[t]       = __float2bfloat16(v0 * inv);
    o[t + 256] = __float2bfloat16(v1 * inv);
    o[t + 512] = __float2bfloat16(v2 * inv);
}

// ---------------------------------------------------------------------------
// Kernel 2: SYMMETRIC bf16 GEMM (s = 10 * fn fn^T) + fused mask reductions.
// R8: only upper-triangle tiles (2080 blocks, bi<=bj). Off-diagonal blocks
// run the direct epilogue (rows i, mask[i][j]) AND a mirror epilogue
// (rows j, mask[j][i]) fed by transposing acc through the staging LDS in
// four 32x128 strips (free after the K-loop). MFMA + fn staging halve;
// mask bytes unchanged (each element consumed exactly once).
// K-loop & direct epilogue identical to R7 (the win config).
// ---------------------------------------------------------------------------
__global__ __launch_bounds__(256, 4) void ntxent_main(
        const __hip_bfloat16* __restrict__ fn,
        const float* __restrict__ pmask, const float* __restrict__ nmask,
        float* __restrict__ negG, float* __restrict__ sG,
        float* __restrict__ pG) {
    __shared__ __align__(16) char smem[32 * TSTRIDE * 4];   // 16.9 KB
    __hip_bfloat16* Is = (__hip_bfloat16*)smem;             // [128*32] bf16
    __hip_bfloat16* Js = Is + 128 * 32;
    float* T = (float*)smem;                                // [32][TSTRIDE]

    const int t = threadIdx.x;
    const int lane = t & 63;
    const int wv = t >> 6;
    const int wm = wv & 1;           // wave's j-half
    const int wn = wv >> 1;          // wave's i-half
    const int q  = lane >> 4;
    const int cl = lane & 15;

    // triangular decode: block bt -> (c, r) with c <= r
    const int bt = blockIdx.x;
    int r = (int)((sqrtf(8.0f * (float)bt + 1.0f) - 1.0f) * 0.5f);
    while ((r + 1) * (r + 2) / 2 <= bt) ++r;
    while (r * (r + 1) / 2 > bt) --r;
    const int c = bt - r * (r + 1) / 2;
    const int rowBase = c * 128;     // i-tile
    const int colBase = r * 128;     // j-tile
    const bool offDiag = (c != r);

    const int rdSw = ((q ^ ((cl >> 1) & 3)) << 4);

    floatx4 acc[4][4];            // [mf (j)][nf (i)]
#pragma unroll
    for (int mf = 0; mf < 4; ++mf)
#pragma unroll
        for (int nf = 0; nf < 4; ++nf)
            acc[mf][nf] = (floatx4){0.f, 0.f, 0.f, 0.f};

    for (int k0 = 0; k0 < DDIM; k0 += 32) {
        __syncthreads();
#pragma unroll
        for (int it = 0; it < 2; ++it) {
            const int s = it * 256 + t;              // 16B slot 0..511
            const int rr = s >> 2;
            const int cg = (s & 3) ^ ((rr >> 1) & 3); // swizzled src chunk
            const __hip_bfloat16* ga = fn + (size_t)(rowBase + rr) * DDIM + k0 + cg * 8;
            const __hip_bfloat16* gb = fn + (size_t)(colBase + rr) * DDIM + k0 + cg * 8;
            __builtin_amdgcn_global_load_lds(
                (const __attribute__((address_space(1))) void*)ga,
                (__attribute__((address_space(3))) void*)((char*)Is + s * 16), 16, 0, 0);
            __builtin_amdgcn_global_load_lds(
                (const __attribute__((address_space(1))) void*)gb,
                (__attribute__((address_space(3))) void*)((char*)Js + s * 16), 16, 0, 0);
        }
        __syncthreads();

        short8 jf[4], if_[4];
#pragma unroll
        for (int mf = 0; mf < 4; ++mf) {
            const int rr = wm * 64 + mf * 16 + cl;
            jf[mf] = *(const short8*)((const char*)Js + rr * 64 + rdSw);
        }
#pragma unroll
        for (int nf = 0; nf < 4; ++nf) {
            const int rr = wn * 64 + nf * 16 + cl;
            if_[nf] = *(const short8*)((const char*)Is + rr * 64 + rdSw);
        }
#pragma unroll
        for (int mf = 0; mf < 4; ++mf)
#pragma unroll
            for (int nf = 0; nf < 4; ++nf)
                acc[mf][nf] = __builtin_amdgcn_mfma_f32_16x16x32_bf16(
                    jf[mf], if_[nf], acc[mf][nf], 0, 0, 0);
    }

    // ---- direct epilogue (rows i, mask[i][j]) ----
    const int col64 = colBase + wm * 64;
    const int jb0 = col64 + q * 4;
#pragma unroll
    for (int nf = 0; nf < 4; ++nf) {
        const int grow = rowBase + wn * 64 + nf * 16 + cl;
        const float* prow = pmask + (size_t)grow * NROWS;
        const float* nrow = nmask + (size_t)grow * NROWS;
        float4 pm4[4], nm4[4];
#pragma unroll
        for (int mf = 0; mf < 4; ++mf) {
            pm4[mf] = *(const float4*)(prow + jb0 + mf * 16);
            nm4[mf] = *(const float4*)(nrow + jb0 + mf * 16);
        }
        float aN = 0.f, aS = 0.f, aP = 0.f;
#pragma unroll
        for (int mf = 0; mf < 4; ++mf) {
            const int jbase = jb0 + mf * 16;
#pragma unroll
            for (int reg = 0; reg < 4; ++reg) {
                float pmv = ((const float*)&pm4[mf])[reg];
                float nmv = ((const float*)&nm4[mf])[reg];
                if (grow == jbase + reg) { pmv = 0.f; nmv = 0.f; }  // diagonal
                float v = acc[mf][nf][reg];
                float e = __builtin_amdgcn_exp2f(v * 14.4269504089f); // e^(10v)
                aN = fmaf(nmv, e, aN);
                aS = fmaf(pmv, v, aS);       // raw acc units; x10 in final_k
                aP += pmv;
            }
        }
        aN += __shfl_xor(aN, 16, 64);  aN += __shfl_xor(aN, 32, 64);
        aS += __shfl_xor(aS, 16, 64);  aS += __shfl_xor(aS, 32, 64);
        aP += __shfl_xor(aP, 16, 64);  aP += __shfl_xor(aP, 32, 64);
        if (q == 0) {
            atomicAdd(&negG[grow], aN);
            atomicAdd(&sG[grow],   aS);
            atomicAdd(&pG[grow],   aP);
        }
    }

    // ---- mirror epilogue (rows j, mask[j][i]) -- off-diagonal blocks only --
    if (offDiag) {
        const int jl2 = t >> 3;              // 0..31: strip-local j row
        const int iseg = (t & 7) * 16;       // 16-float i segment
#pragma unroll
        for (int st = 0; st < 4; ++st) {
            __syncthreads();                 // strip buffer free
            if (wm == (st >> 1)) {           // waves owning this strip's j's
#pragma unroll
                for (int m2 = 0; m2 < 2; ++m2) {
                    const int mf = (st & 1) * 2 + m2;
#pragma unroll
                    for (int nf = 0; nf < 4; ++nf) {
                        const int i = wn * 64 + nf * 16 + cl;
#pragma unroll
                        for (int reg = 0; reg < 4; ++reg) {
                            const int jl = m2 * 16 + q * 4 + reg;
                            T[jl * TSTRIDE + i] = acc[mf][nf][reg];
                        }
                    }
                }
            }
            __syncthreads();
            const int jg = colBase + st * 32 + jl2;
            const float* prow = pmask + (size_t)jg * NROWS + rowBase + iseg;
            const float* nrow = nmask + (size_t)jg * NROWS + rowBase + iseg;
            float4 pm4[4], nm4[4];
#pragma unroll
            for (int u = 0; u < 4; ++u) {
                pm4[u] = *(const float4*)(prow + u * 4);
                nm4[u] = *(const float4*)(nrow + u * 4);
            }
            const float4* tv = (const float4*)(T + jl2 * TSTRIDE + iseg);
            float aN = 0.f, aS = 0.f, aP = 0.f;
#pragma unroll
            for (int u = 0; u < 4; ++u) {
                float4 v4 = tv[u];
#pragma unroll
                for (int e = 0; e < 4; ++e) {
                    float v = ((const float*)&v4)[e];
                    float pmv = ((const float*)&pm4[u])[e];
                    float nmv = ((const float*)&nm4[u])[e];
                    float ex = __builtin_amdgcn_exp2f(v * 14.4269504089f);
                    aN = fmaf(nmv, ex, aN);
                    aS = fmaf(pmv, v, aS);
                    aP += pmv;
                }
            }
            aN += __shfl_xor(aN, 1, 64); aN += __shfl_xor(aN, 2, 64); aN += __shfl_xor(aN, 4, 64);
            aS += __shfl_xor(aS, 1, 64); aS += __shfl_xor(aS, 2, 64); aS += __shfl_xor(aS, 4, 64);
            aP += __shfl_xor(aP, 1, 64); aP += __shfl_xor(aP, 2, 64); aP += __shfl_xor(aP, 4, 64);
            if ((t & 7) == 0) {
                atomicAdd(&negG[jg], aN);
                atomicAdd(&sG[jg],   aS);
                atomicAdd(&pG[jg],   aP);
            }
        }
    }
}

// ---------------------------------------------------------------------------
// Kernel 3: per-row loss assembly + mean
// loss_i = (P*log(neg) - 10*S_raw)/P (P>0 else 0);  out = mean
// ---------------------------------------------------------------------------
__global__ __launch_bounds__(1024) void final_k(const float* __restrict__ negG,
        const float* __restrict__ sG, const float* __restrict__ pG,
        float* __restrict__ out) {
    const int t = threadIdx.x;
    float sum = 0.f;
    for (int i = t; i < NROWS; i += 1024) {
        float P = pG[i];
        if (P > 0.f) {
            sum += (P * logf(negG[i]) - 10.0f * sG[i]) / P;
        }
    }
#pragma unroll
    for (int m = 32; m; m >>= 1) sum += __shfl_xor(sum, m, 64);
    __shared__ float wsum[16];
    if ((t & 63) == 0) wsum[t >> 6] = sum;
    __syncthreads();
    if (t < 16) {
        float v = wsum[t];
#pragma unroll
        for (int m = 8; m; m >>= 1) v += __shfl_xor(v, m, 16);
        if (t == 0) out[0] = v / (float)NROWS;
    }
}

// ---------------------------------------------------------------------------
extern "C" void kernel_launch(void* const* d_in, const int* in_sizes, int n_in,
                              void* d_out, int out_size, void* d_ws, size_t ws_size,
                              hipStream_t stream) {
    const float* feat  = (const float*)d_in[0];
    const float* pmask = (const float*)d_in[1];
    const float* nmask = (const float*)d_in[2];
    float* out = (float*)d_out;

    char* ws = (char*)d_ws;
    __hip_bfloat16* fn = (__hip_bfloat16*)ws;                    // 12,582,912 B
    float* negG = (float*)(ws + 12582912);
    float* sG = negG + NROWS;
    float* pG = sG + NROWS;

    // zero all three row accumulators (ws is re-poisoned before every launch)
    hipMemsetAsync(negG, 0, 3 * NROWS * sizeof(float), stream);

    normalize_k<<<NROWS, 256, 0, stream>>>(feat, fn);

    ntxent_main<<<2080, 256, 0, stream>>>(fn, pmask, nmask, negG, sG, pG);

    final_k<<<1, 1024, 0, stream>>>(negG, sG, pG, out);
}